// Round 5
// baseline (79.220 us; speedup 1.0000x reference)
//
#include <hip/hip_runtime.h>

// HEALPixPad: x (B=2, 12, C=32, 256, 256) f32 -> (B, 12, C, 260, 260) f32, P=2.
// Bulk: 8 blocks/plane, each thread moves 8 independent float4s (deep MLP),
// aligned loads, nontemporal stores. Halo: 1 block/plane runs the
// round-1-verified gather over the 2-wide edge strips.

constexpr int N  = 256;
constexpr int P  = 2;
constexpr int NP = N + 2 * P;        // 260
constexpr int C  = 32;
constexpr int PLANE_OUT = NP * NP;   // 67600
constexpr int PLANE_IN  = N * N;     // 65536
constexpr int BULK_X    = 8;         // bulk blocks per plane
constexpr int ITERS     = (N * (N / 4)) / (BULK_X * 256);  // 16384/2048 = 8

typedef float f32x4 __attribute__((ext_vector_type(4)));

// Per-element gather with the full HEALPix neighbor mapping (round-1 verified).
__device__ __forceinline__ float gather(const float* __restrict__ in,
                                        int basePlane, int face, int i,
                                        int oh, int ow) {
    auto L = [&](int f, int sh, int sw) -> float {
        return in[(size_t)(basePlane + f * C) * PLANE_IN + sh * N + sw];
    };

    float v;
    if (face < 4) {
        // ---- northern polar cap ----
        if (oh < P) {
            if (ow < P)              v = L((i + 2) & 3, P - 1 - oh, P - 1 - ow);
            else if (ow < P + N)     v = L((i + 1) & 3, ow - P, P - 1 - oh);
            else                     v = L((i + 1) & 3, ow - P - N, P - 1 - oh);
        } else if (oh < P + N) {
            int ch = oh - P;
            if (ow < P)              v = L((i + 3) & 3, P - 1 - ow, ch);
            else if (ow < P + N)     v = L(face, ch, ow - P);
            else                     v = L(4 + ((i + 1) & 3), ch, ow - P - N);
        } else {
            int bh = oh - P - N;
            if (ow < P)              v = L((i + 3) & 3, bh, N - P + ow);
            else if (ow < P + N)     v = L(4 + i, bh, ow - P);
            else                     v = L(8 + i, bh, ow - P - N);
        }
    } else if (face < 8) {
        // ---- equatorial belt ----
        if (oh < P) {
            if (ow < P) {
                if (oh == P - 1 && ow == P - 1)
                    v = 0.5f * L(i, N - 1, 0) + 0.5f * L((i + 3) & 3, 0, N - 1);
                else if (oh == P - 1) v = L((i + 3) & 3, 0, N - P + ow);
                else if (ow == P - 1) v = L(i, N - P + oh, 0);
                else                  v = 0.0f;
            }
            else if (ow < P + N)     v = L(i, N - P + oh, ow - P);
            else                     v = L(i, N - P + oh, ow - P - N);
        } else if (oh < P + N) {
            int ch = oh - P;
            if (ow < P)              v = L((i + 3) & 3, ch, N - P + ow);
            else if (ow < P + N)     v = L(face, ch, ow - P);
            else                     v = L(4 + ((i + 1) & 3), ch, ow - P - N);
        } else {
            int bh = oh - P - N;
            if (ow < P)              v = L(4 + ((i + 3) & 3), bh, N - P + ow);
            else if (ow < P + N)     v = L(8 + i, bh, ow - P);
            else {
                int bw = ow - P - N;
                if (bh == 0 && bw == 0)
                    v = 0.5f * L(8 + i, 0, N - 1) + 0.5f * L(8 + ((i + 3) & 3), N - 1, 0);
                else if (bh == 0)     v = L(8 + ((i + 3) & 3), N - 1, bw);
                else if (bw == 0)     v = L(8 + i, bh, N - 1);
                else                  v = 0.0f;
            }
        }
    } else {
        // ---- southern polar cap ----
        if (oh < P) {
            if (ow < P)              v = L(4 + i, N - P + oh, ow);
            else if (ow < P + N)     v = L(4 + i, N - P + oh, ow - P);
            else                     v = L(i, N - P + oh, N - P + (ow - P - N));
        } else if (oh < P + N) {
            int ch = oh - P;
            if (ow < P)              v = L(4 + ((i + 1) & 3), ch, N - P + ow);
            else if (ow < P + N)     v = L(face, ch, ow - P);
            else {
                int bw = ow - P - N;
                v = L(8 + ((i + 1) & 3), N - 1 - bw, ch);
            }
        } else {
            int bh = oh - P - N;
            if (ow < P)              v = L(8 + ((i + 1) & 3), N - P + ow, N - 1 - bh);
            else if (ow < P + N)     v = L(8 + ((i + 3) & 3), ow - P, N - 1 - bh);
            else {
                int bw = ow - P - N;
                v = L(8 + ((i + 3) & 3), N - 1 - bh, N - 1 - bw);
            }
        }
    }
    return v;
}

__global__ __launch_bounds__(256)
void healpix_pad_kernel(const float* __restrict__ in, float* __restrict__ out) {
    const int plane = blockIdx.y;                 // (b*12 + face)*C + c
    const int x     = blockIdx.x;

    float* __restrict__ oplane = out + (size_t)plane * PLANE_OUT;

    if (x < BULK_X) {
        // ---- divergence-free bulk copy with 8 independent float4s per thread
        const float* __restrict__ iplane = in + (size_t)plane * PLANE_IN;
        const int base = x * 256 + threadIdx.x;    // float4 index, stride 2048

        f32x4 v[ITERS];
        #pragma unroll
        for (int it = 0; it < ITERS; ++it) {
            int f4 = base + it * 2048;
            v[it] = *reinterpret_cast<const f32x4*>(iplane + f4 * 4);
        }
        #pragma unroll
        for (int it = 0; it < ITERS; ++it) {
            int f4  = base + it * 2048;
            int row = f4 >> 6;                     // input row
            int c4  = f4 & 63;                     // float4 within row
            float* dst = oplane + (row + P) * NP + c4 * 4 + P;
            __builtin_nontemporal_store(v[it], reinterpret_cast<f32x4*>(dst));
        }
        return;
    }

    // ---- halo block: 772 tasks per plane, 4-iteration task loop
    const int bc   = plane >> 5;                   // b*12 + face   (C=32)
    const int face = bc >= 12 ? bc - 12 : bc;
    const int i    = face & 3;
    const int basePlane = plane - face * C;

    for (int t = threadIdx.x; t < 772; t += 256) {
        if (t < 260) {
            // top rows 0,1 and bottom rows 258,259: one float4 each
            int row = (t < 130) ? (t / 65) : (258 + (t - 130) / 65);
            int j   = (t < 130) ? (t % 65) : ((t - 130) % 65);
            int ow  = 4 * j;
            f32x4 v;
            v.x = gather(in, basePlane, face, i, row, ow);
            v.y = gather(in, basePlane, face, i, row, ow + 1);
            v.z = gather(in, basePlane, face, i, row, ow + 2);
            v.w = gather(in, basePlane, face, i, row, ow + 3);
            *reinterpret_cast<f32x4*>(oplane + row * NP + ow) = v;
        } else if (t < 516) {
            // left strip, interior rows: cols 0,1
            int oh = (t - 260) + P;
            float2 v;
            v.x = gather(in, basePlane, face, i, oh, 0);
            v.y = gather(in, basePlane, face, i, oh, 1);
            *reinterpret_cast<float2*>(oplane + oh * NP) = v;
        } else {
            // right strip, interior rows: cols 258,259
            int oh = (t - 516) + P;
            float2 v;
            v.x = gather(in, basePlane, face, i, oh, NP - 2);
            v.y = gather(in, basePlane, face, i, oh, NP - 1);
            *reinterpret_cast<float2*>(oplane + oh * NP + NP - 2) = v;
        }
    }
}

extern "C" void kernel_launch(void* const* d_in, const int* in_sizes, int n_in,
                              void* d_out, int out_size, void* d_ws, size_t ws_size,
                              hipStream_t stream) {
    const float* in = (const float*)d_in[0];
    float* out = (float*)d_out;
    int planes = out_size / PLANE_OUT;             // 2*12*32 = 768
    dim3 block(256);
    dim3 grid(BULK_X + 1, planes);
    healpix_pad_kernel<<<grid, block, 0, stream>>>(in, out);
}

// Round 6
// 76.558 us; speedup vs baseline: 1.0348x; 1.0348x over previous
//
#include <hip/hip_runtime.h>

// HEALPixPad: x (B=2, 12, C=32, 256, 256) f32 -> (B, 12, C, 260, 260) f32, P=2.
// Whole-row waves: every output row (260 f32 = 65 aligned float4) is written
// completely by one wave -> dense, fully line-aligned NT write stream.
// Lanes 1..63 do float4 j=1..63 (two 8B loads each, input shifted -2 cols);
// lane 0 does edge float4s j=0 and j=64 (gather halo + float2). Top/bottom
// 2 rows: one gather block per plane (round-1-verified mapping).

constexpr int N  = 256;
constexpr int P  = 2;
constexpr int NP = N + 2 * P;        // 260
constexpr int C  = 32;
constexpr int PLANE_OUT = NP * NP;   // 67600
constexpr int PLANE_IN  = N * N;     // 65536
constexpr int BULK_X    = 32;        // 32 blocks * 4 waves * 2 rows = 256 rows

typedef float f32x4 __attribute__((ext_vector_type(4)));

// Per-element gather with the full HEALPix neighbor mapping (round-1 verified).
__device__ __forceinline__ float gather(const float* __restrict__ in,
                                        int basePlane, int face, int i,
                                        int oh, int ow) {
    auto L = [&](int f, int sh, int sw) -> float {
        return in[(size_t)(basePlane + f * C) * PLANE_IN + sh * N + sw];
    };

    float v;
    if (face < 4) {
        // ---- northern polar cap ----
        if (oh < P) {
            if (ow < P)              v = L((i + 2) & 3, P - 1 - oh, P - 1 - ow);
            else if (ow < P + N)     v = L((i + 1) & 3, ow - P, P - 1 - oh);
            else                     v = L((i + 1) & 3, ow - P - N, P - 1 - oh);
        } else if (oh < P + N) {
            int ch = oh - P;
            if (ow < P)              v = L((i + 3) & 3, P - 1 - ow, ch);
            else if (ow < P + N)     v = L(face, ch, ow - P);
            else                     v = L(4 + ((i + 1) & 3), ch, ow - P - N);
        } else {
            int bh = oh - P - N;
            if (ow < P)              v = L((i + 3) & 3, bh, N - P + ow);
            else if (ow < P + N)     v = L(4 + i, bh, ow - P);
            else                     v = L(8 + i, bh, ow - P - N);
        }
    } else if (face < 8) {
        // ---- equatorial belt ----
        if (oh < P) {
            if (ow < P) {
                if (oh == P - 1 && ow == P - 1)
                    v = 0.5f * L(i, N - 1, 0) + 0.5f * L((i + 3) & 3, 0, N - 1);
                else if (oh == P - 1) v = L((i + 3) & 3, 0, N - P + ow);
                else if (ow == P - 1) v = L(i, N - P + oh, 0);
                else                  v = 0.0f;
            }
            else if (ow < P + N)     v = L(i, N - P + oh, ow - P);
            else                     v = L(i, N - P + oh, ow - P - N);
        } else if (oh < P + N) {
            int ch = oh - P;
            if (ow < P)              v = L((i + 3) & 3, ch, N - P + ow);
            else if (ow < P + N)     v = L(face, ch, ow - P);
            else                     v = L(4 + ((i + 1) & 3), ch, ow - P - N);
        } else {
            int bh = oh - P - N;
            if (ow < P)              v = L(4 + ((i + 3) & 3), bh, N - P + ow);
            else if (ow < P + N)     v = L(8 + i, bh, ow - P);
            else {
                int bw = ow - P - N;
                if (bh == 0 && bw == 0)
                    v = 0.5f * L(8 + i, 0, N - 1) + 0.5f * L(8 + ((i + 3) & 3), N - 1, 0);
                else if (bh == 0)     v = L(8 + ((i + 3) & 3), N - 1, bw);
                else if (bw == 0)     v = L(8 + i, bh, N - 1);
                else                  v = 0.0f;
            }
        }
    } else {
        // ---- southern polar cap ----
        if (oh < P) {
            if (ow < P)              v = L(4 + i, N - P + oh, ow);
            else if (ow < P + N)     v = L(4 + i, N - P + oh, ow - P);
            else                     v = L(i, N - P + oh, N - P + (ow - P - N));
        } else if (oh < P + N) {
            int ch = oh - P;
            if (ow < P)              v = L(4 + ((i + 1) & 3), ch, N - P + ow);
            else if (ow < P + N)     v = L(face, ch, ow - P);
            else {
                int bw = ow - P - N;
                v = L(8 + ((i + 1) & 3), N - 1 - bw, ch);
            }
        } else {
            int bh = oh - P - N;
            if (ow < P)              v = L(8 + ((i + 1) & 3), N - P + ow, N - 1 - bh);
            else if (ow < P + N)     v = L(8 + ((i + 3) & 3), ow - P, N - 1 - bh);
            else {
                int bw = ow - P - N;
                v = L(8 + ((i + 3) & 3), N - 1 - bh, N - 1 - bw);
            }
        }
    }
    return v;
}

__global__ __launch_bounds__(256)
void healpix_pad_kernel(const float* __restrict__ in, float* __restrict__ out) {
    const int plane = blockIdx.y;                 // (b*12 + face)*C + c
    const int x     = blockIdx.x;

    float* __restrict__ oplane = out + (size_t)plane * PLANE_OUT;
    const float* __restrict__ iplane = in + (size_t)plane * PLANE_IN;

    const int bc   = plane >> 5;                   // b*12 + face   (C=32)
    const int face = bc >= 12 ? bc - 12 : bc;
    const int i    = face & 3;
    const int basePlane = plane - face * C;

    if (x < BULK_X) {
        // ---- interior rows 2..257: one wave per output row, 2 rows per wave
        const int w = threadIdx.x >> 6;            // wave 0..3
        const int l = threadIdx.x & 63;            // lane
        const int r0 = x * 8 + w;                  // input row for iteration 0

        #pragma unroll
        for (int k = 0; k < 2; ++k) {
            const int r  = r0 + 4 * k;             // input row 0..255
            const int oh = r + P;                  // output row 2..257
            const float* __restrict__ src = iplane + r * N;
            float* __restrict__ dst = oplane + oh * NP;     // 16B-aligned

            if (l != 0) {
                // j = l in [1,64): out cols 4j..4j+3 <- in cols 4j-2..4j+1
                float2 a = *reinterpret_cast<const float2*>(src + 4 * l - 2);
                float2 b = *reinterpret_cast<const float2*>(src + 4 * l);
                f32x4 v = {a.x, a.y, b.x, b.y};
                __builtin_nontemporal_store(v, reinterpret_cast<f32x4*>(dst + 4 * l));
            } else {
                // j = 0: cols 0,1 halo + cols 2,3 = in cols 0,1
                f32x4 v0;
                v0.x = gather(in, basePlane, face, i, oh, 0);
                v0.y = gather(in, basePlane, face, i, oh, 1);
                float2 a = *reinterpret_cast<const float2*>(src);
                v0.z = a.x; v0.w = a.y;
                __builtin_nontemporal_store(v0, reinterpret_cast<f32x4*>(dst));
                // j = 64: cols 256,257 = in cols 254,255 + cols 258,259 halo
                f32x4 v1;
                float2 b = *reinterpret_cast<const float2*>(src + N - 2);
                v1.x = b.x; v1.y = b.y;
                v1.z = gather(in, basePlane, face, i, oh, NP - 2);
                v1.w = gather(in, basePlane, face, i, oh, NP - 1);
                __builtin_nontemporal_store(v1, reinterpret_cast<f32x4*>(dst + N));
            }
        }
        return;
    }

    // ---- top rows 0,1 and bottom rows 258,259: 4 rows x 65 float4 = 260 tasks
    for (int t = threadIdx.x; t < 4 * 65; t += 256) {
        int q   = t / 65;                          // 0..3
        int row = (q < 2) ? q : 256 + q;           // 0,1,258,259
        int j   = t - q * 65;
        int ow  = 4 * j;
        f32x4 v;
        v.x = gather(in, basePlane, face, i, row, ow);
        v.y = gather(in, basePlane, face, i, row, ow + 1);
        v.z = gather(in, basePlane, face, i, row, ow + 2);
        v.w = gather(in, basePlane, face, i, row, ow + 3);
        __builtin_nontemporal_store(v, reinterpret_cast<f32x4*>(oplane + row * NP + ow));
    }
}

extern "C" void kernel_launch(void* const* d_in, const int* in_sizes, int n_in,
                              void* d_out, int out_size, void* d_ws, size_t ws_size,
                              hipStream_t stream) {
    const float* in = (const float*)d_in[0];
    float* out = (float*)d_out;
    int planes = out_size / PLANE_OUT;             // 2*12*32 = 768
    dim3 block(256);
    dim3 grid(BULK_X + 1, planes);
    healpix_pad_kernel<<<grid, block, 0, stream>>>(in, out);
}

// Round 7
// 72.146 us; speedup vs baseline: 1.0981x; 1.0612x over previous
//
#include <hip/hip_runtime.h>

// HEALPixPad: x (B=2, 12, C=32, 256, 256) f32 -> (B, 12, C, 260, 260) f32, P=2.
// Span waves: 4 output rows = 4160 B = exactly 65 cache lines, 64B-aligned
// (plane stride 270400 % 64 == 0). Each wave writes one 4-row span as 5
// contiguous wave-wide NT float4 stores -> full-line write-combining, no
// partial-line amplification. j==0/64 chunks carry the left/right gather
// halo; groups 0 and 64 carry the top/bottom gather rows.

constexpr int N  = 256;
constexpr int P  = 2;
constexpr int NP = N + 2 * P;        // 260
constexpr int C  = 32;
constexpr int PLANE_OUT = NP * NP;   // 67600
constexpr int PLANE_IN  = N * N;     // 65536

typedef float f32x4 __attribute__((ext_vector_type(4)));

// Per-element gather with the full HEALPix neighbor mapping (round-1 verified).
__device__ __forceinline__ float gather(const float* __restrict__ in,
                                        int basePlane, int face, int i,
                                        int oh, int ow) {
    auto L = [&](int f, int sh, int sw) -> float {
        return in[(size_t)(basePlane + f * C) * PLANE_IN + sh * N + sw];
    };

    float v;
    if (face < 4) {
        // ---- northern polar cap ----
        if (oh < P) {
            if (ow < P)              v = L((i + 2) & 3, P - 1 - oh, P - 1 - ow);
            else if (ow < P + N)     v = L((i + 1) & 3, ow - P, P - 1 - oh);
            else                     v = L((i + 1) & 3, ow - P - N, P - 1 - oh);
        } else if (oh < P + N) {
            int ch = oh - P;
            if (ow < P)              v = L((i + 3) & 3, P - 1 - ow, ch);
            else if (ow < P + N)     v = L(face, ch, ow - P);
            else                     v = L(4 + ((i + 1) & 3), ch, ow - P - N);
        } else {
            int bh = oh - P - N;
            if (ow < P)              v = L((i + 3) & 3, bh, N - P + ow);
            else if (ow < P + N)     v = L(4 + i, bh, ow - P);
            else                     v = L(8 + i, bh, ow - P - N);
        }
    } else if (face < 8) {
        // ---- equatorial belt ----
        if (oh < P) {
            if (ow < P) {
                if (oh == P - 1 && ow == P - 1)
                    v = 0.5f * L(i, N - 1, 0) + 0.5f * L((i + 3) & 3, 0, N - 1);
                else if (oh == P - 1) v = L((i + 3) & 3, 0, N - P + ow);
                else if (ow == P - 1) v = L(i, N - P + oh, 0);
                else                  v = 0.0f;
            }
            else if (ow < P + N)     v = L(i, N - P + oh, ow - P);
            else                     v = L(i, N - P + oh, ow - P - N);
        } else if (oh < P + N) {
            int ch = oh - P;
            if (ow < P)              v = L((i + 3) & 3, ch, N - P + ow);
            else if (ow < P + N)     v = L(face, ch, ow - P);
            else                     v = L(4 + ((i + 1) & 3), ch, ow - P - N);
        } else {
            int bh = oh - P - N;
            if (ow < P)              v = L(4 + ((i + 3) & 3), bh, N - P + ow);
            else if (ow < P + N)     v = L(8 + i, bh, ow - P);
            else {
                int bw = ow - P - N;
                if (bh == 0 && bw == 0)
                    v = 0.5f * L(8 + i, 0, N - 1) + 0.5f * L(8 + ((i + 3) & 3), N - 1, 0);
                else if (bh == 0)     v = L(8 + ((i + 3) & 3), N - 1, bw);
                else if (bw == 0)     v = L(8 + i, bh, N - 1);
                else                  v = 0.0f;
            }
        }
    } else {
        // ---- southern polar cap ----
        if (oh < P) {
            if (ow < P)              v = L(4 + i, N - P + oh, ow);
            else if (ow < P + N)     v = L(4 + i, N - P + oh, ow - P);
            else                     v = L(i, N - P + oh, N - P + (ow - P - N));
        } else if (oh < P + N) {
            int ch = oh - P;
            if (ow < P)              v = L(4 + ((i + 1) & 3), ch, N - P + ow);
            else if (ow < P + N)     v = L(face, ch, ow - P);
            else {
                int bw = ow - P - N;
                v = L(8 + ((i + 1) & 3), N - 1 - bw, ch);
            }
        } else {
            int bh = oh - P - N;
            if (ow < P)              v = L(8 + ((i + 1) & 3), N - P + ow, N - 1 - bh);
            else if (ow < P + N)     v = L(8 + ((i + 3) & 3), ow - P, N - 1 - bh);
            else {
                int bw = ow - P - N;
                v = L(8 + ((i + 3) & 3), N - 1 - bh, N - 1 - bw);
            }
        }
    }
    return v;
}

__global__ __launch_bounds__(256)
void healpix_pad_kernel(const float* __restrict__ in, float* __restrict__ out) {
    const int plane = blockIdx.y;                  // (b*12 + face)*C + c
    const int g     = blockIdx.x * 4 + (threadIdx.x >> 6);  // 4-row group 0..64
    if (g > 64) return;
    const int l     = threadIdx.x & 63;

    float* __restrict__ oplane = out + (size_t)plane * PLANE_OUT;
    const float* __restrict__ iplane = in + (size_t)plane * PLANE_IN;

    const int bc   = plane >> 5;                   // b*12 + face   (C=32)
    const int face = bc >= 12 ? bc - 12 : bc;
    const int i    = face & 3;
    const int basePlane = plane - face * C;
    const int r0   = g * 4;                        // first output row of span

    #pragma unroll
    for (int it = 0; it < 5; ++it) {
        const int c = it * 64 + l;                 // chunk 0..259 within span
        if (c >= 260) break;                       // only last iter, 4 lanes live
        const int q   = c / 65;                    // row within span (magic mul)
        const int j   = c - q * 65;                // float4 index within row
        const int row = r0 + q;                    // output row
        const int ow  = 4 * j;

        f32x4 v;
        if (row >= P && row < P + N) {
            const float* __restrict__ src = iplane + (row - P) * N;
            if (j == 0) {
                v.x = gather(in, basePlane, face, i, row, 0);
                v.y = gather(in, basePlane, face, i, row, 1);
                float2 a = *reinterpret_cast<const float2*>(src);
                v.z = a.x; v.w = a.y;
            } else if (j == 64) {
                float2 b = *reinterpret_cast<const float2*>(src + N - 2);
                v.x = b.x; v.y = b.y;
                v.z = gather(in, basePlane, face, i, row, NP - 2);
                v.w = gather(in, basePlane, face, i, row, NP - 1);
            } else {
                float2 a = *reinterpret_cast<const float2*>(src + ow - 2);
                float2 b = *reinterpret_cast<const float2*>(src + ow);
                v = f32x4{a.x, a.y, b.x, b.y};
            }
        } else {
            // top rows 0,1 / bottom rows 258,259: full gather
            v.x = gather(in, basePlane, face, i, row, ow);
            v.y = gather(in, basePlane, face, i, row, ow + 1);
            v.z = gather(in, basePlane, face, i, row, ow + 2);
            v.w = gather(in, basePlane, face, i, row, ow + 3);
        }
        __builtin_nontemporal_store(v, reinterpret_cast<f32x4*>(oplane + row * NP + ow));
    }
}

extern "C" void kernel_launch(void* const* d_in, const int* in_sizes, int n_in,
                              void* d_out, int out_size, void* d_ws, size_t ws_size,
                              hipStream_t stream) {
    const float* in = (const float*)d_in[0];
    float* out = (float*)d_out;
    int planes = out_size / PLANE_OUT;             // 2*12*32 = 768
    dim3 block(256);
    dim3 grid(17, planes);                         // 17*4 waves >= 65 groups
    healpix_pad_kernel<<<grid, block, 0, stream>>>(in, out);
}

// Round 8
// 70.735 us; speedup vs baseline: 1.1200x; 1.0200x over previous
//
#include <hip/hip_runtime.h>

// HEALPixPad: x (B=2, 12, C=32, 256, 256) f32 -> (B, 12, C, 260, 260) f32, P=2.
// Round 8: divergence-free bulk via LDS staging.
//   - Store unit: 4-output-row span = 4160 B = exactly 65 cache lines (aligned).
//     One wave per span, 5 wave-wide NT float4 stores -> zero write amplification
//     (verified R7: WRITE_SIZE at ideal).
//   - Phase 0: waves issue all interior float2 loads up front.
//   - Phase 1: 64 threads/block compute left/right edge halo values into LDS
//     (divergent gather confined, overlapped with phase-0 loads); blocks 0/16
//     additionally fill full top/bottom gather rows into LDS.
//   - Phase 2: branch-light selects, 5 back-to-back NT span stores.

constexpr int N  = 256;
constexpr int P  = 2;
constexpr int NP = N + 2 * P;        // 260
constexpr int C  = 32;
constexpr int PLANE_OUT = NP * NP;   // 67600
constexpr int PLANE_IN  = N * N;     // 65536

typedef float f32x4 __attribute__((ext_vector_type(4)));

// Per-element gather with the full HEALPix neighbor mapping (round-1 verified).
__device__ __forceinline__ float gather(const float* __restrict__ in,
                                        int basePlane, int face, int i,
                                        int oh, int ow) {
    auto L = [&](int f, int sh, int sw) -> float {
        return in[(size_t)(basePlane + f * C) * PLANE_IN + sh * N + sw];
    };

    float v;
    if (face < 4) {
        // ---- northern polar cap ----
        if (oh < P) {
            if (ow < P)              v = L((i + 2) & 3, P - 1 - oh, P - 1 - ow);
            else if (ow < P + N)     v = L((i + 1) & 3, ow - P, P - 1 - oh);
            else                     v = L((i + 1) & 3, ow - P - N, P - 1 - oh);
        } else if (oh < P + N) {
            int ch = oh - P;
            if (ow < P)              v = L((i + 3) & 3, P - 1 - ow, ch);
            else if (ow < P + N)     v = L(face, ch, ow - P);
            else                     v = L(4 + ((i + 1) & 3), ch, ow - P - N);
        } else {
            int bh = oh - P - N;
            if (ow < P)              v = L((i + 3) & 3, bh, N - P + ow);
            else if (ow < P + N)     v = L(4 + i, bh, ow - P);
            else                     v = L(8 + i, bh, ow - P - N);
        }
    } else if (face < 8) {
        // ---- equatorial belt ----
        if (oh < P) {
            if (ow < P) {
                if (oh == P - 1 && ow == P - 1)
                    v = 0.5f * L(i, N - 1, 0) + 0.5f * L((i + 3) & 3, 0, N - 1);
                else if (oh == P - 1) v = L((i + 3) & 3, 0, N - P + ow);
                else if (ow == P - 1) v = L(i, N - P + oh, 0);
                else                  v = 0.0f;
            }
            else if (ow < P + N)     v = L(i, N - P + oh, ow - P);
            else                     v = L(i, N - P + oh, ow - P - N);
        } else if (oh < P + N) {
            int ch = oh - P;
            if (ow < P)              v = L((i + 3) & 3, ch, N - P + ow);
            else if (ow < P + N)     v = L(face, ch, ow - P);
            else                     v = L(4 + ((i + 1) & 3), ch, ow - P - N);
        } else {
            int bh = oh - P - N;
            if (ow < P)              v = L(4 + ((i + 3) & 3), bh, N - P + ow);
            else if (ow < P + N)     v = L(8 + i, bh, ow - P);
            else {
                int bw = ow - P - N;
                if (bh == 0 && bw == 0)
                    v = 0.5f * L(8 + i, 0, N - 1) + 0.5f * L(8 + ((i + 3) & 3), N - 1, 0);
                else if (bh == 0)     v = L(8 + ((i + 3) & 3), N - 1, bw);
                else if (bw == 0)     v = L(8 + i, bh, N - 1);
                else                  v = 0.0f;
            }
        }
    } else {
        // ---- southern polar cap ----
        if (oh < P) {
            if (ow < P)              v = L(4 + i, N - P + oh, ow);
            else if (ow < P + N)     v = L(4 + i, N - P + oh, ow - P);
            else                     v = L(i, N - P + oh, N - P + (ow - P - N));
        } else if (oh < P + N) {
            int ch = oh - P;
            if (ow < P)              v = L(4 + ((i + 1) & 3), ch, N - P + ow);
            else if (ow < P + N)     v = L(face, ch, ow - P);
            else {
                int bw = ow - P - N;
                v = L(8 + ((i + 1) & 3), N - 1 - bw, ch);
            }
        } else {
            int bh = oh - P - N;
            if (ow < P)              v = L(8 + ((i + 1) & 3), N - P + ow, N - 1 - bh);
            else if (ow < P + N)     v = L(8 + ((i + 3) & 3), ow - P, N - 1 - bh);
            else {
                int bw = ow - P - N;
                v = L(8 + ((i + 3) & 3), N - 1 - bh, N - 1 - bw);
            }
        }
    }
    return v;
}

__global__ __launch_bounds__(256)
void healpix_pad_kernel(const float* __restrict__ in, float* __restrict__ out) {
    __shared__ float edges[16][4];                     // [local row][l0,l1,r258,r259]
    __shared__ __align__(16) float rowbuf[2][NP];      // top or bottom gather rows

    const int plane = blockIdx.y;                  // (b*12 + face)*C + c
    const int bx    = blockIdx.x;                  // 0..16
    const int tid   = threadIdx.x;
    const int w     = tid >> 6;
    const int l     = tid & 63;
    const int s     = bx * 4 + w;                  // span id (4 output rows each)

    const int bc   = plane >> 5;                   // b*12 + face   (C=32)
    const int face = bc >= 12 ? bc - 12 : bc;
    const int fi   = face & 3;
    const int basePlane = plane - face * C;
    const float* __restrict__ iplane = in + (size_t)plane * PLANE_IN;
    float* __restrict__ oplane = out + (size_t)plane * PLANE_OUT;

    // ---- phase 0: issue all interior loads for my span (overlap with phase 1)
    const int r0 = s * 4;
    float2 A[5], B[5];
    if (s <= 64) {
        #pragma unroll
        for (int it = 0; it < 5; ++it) {
            int c = it * 64 + l; if (c > 259) c = 259;       // clamp dead lanes
            int q = c / 65, j = c - q * 65;
            int row = r0 + q;
            int ir  = row - P;                                // clamped input row
            ir = ir < 0 ? 0 : (ir > 255 ? 255 : ir);
            const float* src = iplane + ir * N;
            int off1 = (j == 0) ? 0 : (4 * j - 2);            // j==64 -> 254
            int off2 = (j >= 64) ? 252 : 4 * j;               // dummy for j==64
            A[it] = *reinterpret_cast<const float2*>(src + off1);
            B[it] = *reinterpret_cast<const float2*>(src + off2);
        }
    }

    // ---- phase 1: edge halo values into LDS (divergence confined here)
    if (tid < 64) {
        int row = bx * 16 + (tid >> 2);
        if (row >= P && row <= 257) {
            int e  = tid & 3;
            int ow = (e < 2) ? e : 256 + e;                   // 0,1,258,259
            edges[tid >> 2][e] = gather(in, basePlane, face, fi, row, ow);
        }
    }
    if (bx == 0 || bx == 16) {
        for (int t = tid; t < 2 * NP; t += 256) {
            int r01 = t >= NP ? 1 : 0;
            int col = t - NP * r01;
            int oh  = (bx == 0) ? r01 : 258 + r01;
            rowbuf[r01][col] = gather(in, basePlane, face, fi, oh, col);
        }
    }
    __syncthreads();

    if (s > 64) return;

    // ---- phase 2: branch-light assemble + 5 full-line NT span stores
    #pragma unroll
    for (int it = 0; it < 5; ++it) {
        int c = it * 64 + l;
        if (c > 259) continue;                                // dead lanes (it==4)
        int q = c / 65, j = c - q * 65;
        int row = r0 + q;
        int ow  = 4 * j;

        f32x4 v;
        if (row < P || row > 257) {
            int rb = row < P ? row : row - 258;
            v = *reinterpret_cast<const f32x4*>(&rowbuf[rb][ow]);
        } else {
            int rl = row - bx * 16;
            float e0 = edges[rl][0], e1 = edges[rl][1];
            float e2 = edges[rl][2], e3 = edges[rl][3];
            float x  = (j == 0) ? e0 : A[it].x;
            float y  = (j == 0) ? e1 : A[it].y;
            float z  = (j == 0) ? A[it].x : ((j == 64) ? e2 : B[it].x);
            float wv = (j == 0) ? A[it].y : ((j == 64) ? e3 : B[it].y);
            v = f32x4{x, y, z, wv};
        }
        __builtin_nontemporal_store(v, reinterpret_cast<f32x4*>(oplane + row * NP + ow));
    }
}

extern "C" void kernel_launch(void* const* d_in, const int* in_sizes, int n_in,
                              void* d_out, int out_size, void* d_ws, size_t ws_size,
                              hipStream_t stream) {
    const float* in = (const float*)d_in[0];
    float* out = (float*)d_out;
    int planes = out_size / PLANE_OUT;             // 2*12*32 = 768
    dim3 block(256);
    dim3 grid(17, planes);                         // 17 blocks x 4 spans >= 65 spans
    healpix_pad_kernel<<<grid, block, 0, stream>>>(in, out);
}